// Round 5
// baseline (56.986 us; speedup 1.0000x reference)
//
#include <hip/hip_runtime.h>

#define NN 16
constexpr int BB = 32, CIN = 64, HH = 112, WW = 112;
constexpr int HWC = HH * WW;          // 12544
constexpr int COUT = 128, HW2 = 56 * 56;
constexpr int NE = 64;
constexpr int NQ = HWC / 4;           // 3136 float4 pixels per image
constexpr int QPB = 64;               // pixel-quads per conv block
constexpr int BPI = NQ / QPB;         // 49 conv blocks per image (exact)
constexpr int PF4 = COUT * HW2 / 4;   // 100352 float4 per batch
constexpr int NB1 = BB * BPI;         // 1568 conv blocks
constexpr int N4  = BB * PF4;         // 3211264 output float4
constexpr int WPB = N4 / NB1 / 256;   // 8 warm/scale float4 per thread (exact)

// ---------------- Kernel 1: 1x1 conv + segment scatter + B_fon L3 warm -----
__global__ __launch_bounds__(256) void k_conv_seg(
    const float* __restrict__ Bfor, const int* __restrict__ seg,
    const float* __restrict__ convw, const float* __restrict__ Bfon,
    float* __restrict__ part, float* __restrict__ dump)
{
    __shared__ float w[CIN];
    __shared__ float ps[4][QPB * 5];    // [cg][quad*5+px], stride-5 bank skew
    __shared__ float acc[8 * 80];       // [replica][node*5+st], skewed banks
    const int tid = threadIdx.x;
    const int bid = blockIdx.x;
    const int b   = bid / BPI;
    const int blk = bid % BPI;
    const int cg  = tid >> 6;           // channel group == wave id
    const int l   = tid & 63;           // quad lane

    // hoisted seg load (this thread's scatter pixel)
    const int pp  = blk * 256 + tid;
    const int sgv = seg[(size_t)b * HWC + pp];

    if (tid < CIN) w[tid] = convw[tid];
    for (int i = tid; i < 8 * 80; i += 256) acc[i] = 0.f;

    const int p = (blk * QPB + l) * 4;
    const float* base = Bfor + (size_t)b * CIN * HWC + (size_t)(cg * 16) * HWC + p;

    float4 s = make_float4(0.f, 0.f, 0.f, 0.f);
    #pragma unroll
    for (int cc = 0; cc < 16; ++cc) {
        const float4 v = *reinterpret_cast<const float4*>(base + (size_t)cc * HWC);
        const float wc = w[cg * 16 + cc];
        s.x = fmaf(v.x, wc, s.x);
        s.y = fmaf(v.y, wc, s.y);
        s.z = fmaf(v.z, wc, s.z);
        s.w = fmaf(v.w, wc, s.w);
    }
    __syncthreads();   // (covers w[] + acc init; conv loop used w, see note)
    ps[cg][l * 5 + 0] = s.x;
    ps[cg][l * 5 + 1] = s.y;
    ps[cg][l * 5 + 2] = s.z;
    ps[cg][l * 5 + 3] = s.w;

    // ---- B_fon L3 warm: this block's 2048-float4 slice, fire-and-fold ----
    const float4* wf = reinterpret_cast<const float4*>(Bfon) + (size_t)bid * 2048 + tid;
    float4 wa = make_float4(0.f, 0.f, 0.f, 0.f);
    #pragma unroll
    for (int j = 0; j < WPB; ++j) {
        const float4 v = wf[j * 256];
        wa.x += v.x; wa.y += v.y; wa.z += v.z; wa.w += v.w;
    }
    __syncthreads();

    {   // parallel scatter: thread t -> pixel pp
        const int q  = tid >> 2, px = tid & 3;
        const float v = ps[0][q * 5 + px] + ps[1][q * 5 + px]
                      + ps[2][q * 5 + px] + ps[3][q * 5 + px];
        const float row = (float)(pp / WW);
        const float col = (float)(pp % WW);
        const int k = tid & 7;                      // replica
        float* a = &acc[k * 80 + sgv * 5];
        atomicAdd(a + 0, row);
        atomicAdd(a + 1, col);
        atomicAdd(a + 2, v);
        atomicAdd(a + 3, 1.f);
    }
    __syncthreads();

    if (tid < NN * 4) {
        const int node = tid >> 2, st = tid & 3;
        float v = 0.f;
        #pragma unroll
        for (int k = 0; k < 8; ++k) v += acc[k * 80 + node * 5 + st];
        part[((b * BPI + blk) * NN + node) * 4 + st] = v;
    }
    // keep warm loads live: one tiny reduced store per block
    if ((tid & 63) == 0) {
        const float t0 = wa.x + wa.y + wa.z + wa.w;
        dump[bid * 4 + cg] = t0;
    }
}

// ---------------- Kernel 2: tiny graph network -> G[32][128] ---------------
__global__ __launch_bounds__(256) void k_graph(
    const float* __restrict__ part, const int* __restrict__ src,
    const int* __restrict__ dst,  const float* __restrict__ convb,
    const float* __restrict__ W1, const float* __restrict__ b1,
    const float* __restrict__ W2, const float* __restrict__ b2,
    const float* __restrict__ fcw, const float* __restrict__ fcb,
    float* __restrict__ G)
{
    const int b = blockIdx.x, tid = threadIdx.x;

    __shared__ float X[NN][4];
    __shared__ float A[NN][NN];
    __shared__ float nrm[NN];
    __shared__ float h1s[NN][32];
    __shared__ float agg[NN][32];
    __shared__ float pred[4][64];
    __shared__ float gpart[2][COUT];

    {   // reduce 49 conv-block partials: 4 chunks x <=13 loads, coalesced
        const int id = tid & 63, chunk = tid >> 6;
        float v = 0.f;
        const int k0 = chunk * 13, k1e = (k0 + 13 < BPI) ? k0 + 13 : BPI;
        for (int k = k0; k < k1e; ++k) v += part[(size_t)(b * BPI + k) * 64 + id];
        pred[chunk][id] = v;
    }
    for (int i = tid; i < NN * NN; i += 256) ((float*)A)[i] = 0.f;
    __syncthreads();

    if (tid < 64) {
        const int node = tid >> 2, st = tid & 3;
        X[node][st] = pred[0][tid] + pred[1][tid] + pred[2][tid] + pred[3][tid];
    }
    __syncthreads();

    if (tid < NN) {
        const float cnt = X[tid][3];
        const float cs  = fmaxf(cnt, 1.f);
        X[tid][0] = X[tid][0] / cs;
        X[tid][1] = X[tid][1] / cs;
        X[tid][2] = (X[tid][2] + cnt * convb[0]) / cs;
    }
    __syncthreads();

    if (tid < 2) {   // normalize cols 2,3 (mean, std ddof=1)
        const int c = 2 + tid;
        float mu = 0.f;
        for (int i = 0; i < NN; ++i) mu += X[i][c];
        mu *= (1.f / NN);
        float var = 0.f;
        for (int i = 0; i < NN; ++i) { const float d = X[i][c] - mu; var = fmaf(d, d, var); }
        var *= (1.f / (NN - 1));
        const float inv = 1.f / (sqrtf(var) + 1.f);
        for (int i = 0; i < NN; ++i) X[i][c] = (X[i][c] - mu) * inv;
    }
    if (tid >= 64 && tid < 64 + NE) {   // adjacency (idempotent)
        const int e = tid - 64;
        const int s = src[b * NE + e], d = dst[b * NE + e];
        A[s][d] = 1.f;
        A[d][s] = 1.f;
    }
    __syncthreads();

    if (tid < NN) {
        float rs = 0.f;
        for (int j = 0; j < NN; ++j) rs += A[tid][j];
        nrm[tid] = 1.f / sqrtf(fmaxf(rs, 1.f));
    }
    __syncthreads();

    if (tid < NN * 4) {   // agg1 (16x4)
        const int i = tid >> 2, k = tid & 3;
        float s = 0.f;
        for (int j = 0; j < NN; ++j) s = fmaf(A[i][j] * nrm[j], X[j][k], s);
        agg[i][k] = s;
    }
    __syncthreads();

    for (int t = tid; t < NN * 32; t += 256) {   // h1 (16x32)
        const int i = t >> 5, f = t & 31;
        float s = 0.f;
        #pragma unroll
        for (int k = 0; k < 4; ++k) s = fmaf(agg[i][k], W1[k * 32 + f], s);
        h1s[i][f] = fmaxf(fmaf(nrm[i], s, b1[f]), 0.f);
    }
    __syncthreads();

    for (int t = tid; t < NN * 32; t += 256) {   // agg2 (16x32)
        const int i = t >> 5, k = t & 31;
        float s = 0.f;
        for (int j = 0; j < NN; ++j) s = fmaf(A[i][j] * nrm[j], h1s[j][k], s);
        agg[i][k] = s;
    }
    __syncthreads();

    {   // h2 + FC, i-range split across 2 half-blocks
        const int f = tid & 127, half = tid >> 7;
        float g = 0.f;
        const float bf = b2[f];
        for (int i = half * 8; i < half * 8 + 8; ++i) {
            float s = 0.f;
            #pragma unroll
            for (int k = 0; k < 32; ++k) s = fmaf(agg[i][k], W2[k * COUT + f], s);
            g = fmaf(fcw[i], fmaxf(fmaf(nrm[i], s, bf), 0.f), g);
        }
        gpart[half][f] = g;
    }
    __syncthreads();
    if (tid < COUT) G[b * COUT + tid] = gpart[0][tid] + gpart[1][tid] + fcb[0];
}

// ---------------- Kernel 3: pure stream out = G[b,c] * B_fon ---------------
__global__ __launch_bounds__(256) void k_scale(
    const float* __restrict__ Bfon, const float* __restrict__ G,
    float* __restrict__ out)
{
    const int t0 = blockIdx.x * 256 + threadIdx.x;
    const float4* bf4 = reinterpret_cast<const float4*>(Bfon);
    float4*       ob4 = reinterpret_cast<float4*>(out);
    #pragma unroll
    for (int j = 0; j < WPB; ++j) {
        const int t = t0 + j * (NB1 * 256);
        const float4 v = bf4[t];
        const float  g = G[t / (HW2 / 4)];   // 784 float4 per (b,c) plane
        ob4[t] = make_float4(v.x * g, v.y * g, v.z * g, v.w * g);
    }
}

extern "C" void kernel_launch(void* const* d_in, const int* in_sizes, int n_in,
                              void* d_out, int out_size, void* d_ws, size_t ws_size,
                              hipStream_t stream)
{
    const float* Bfor  = (const float*)d_in[0];
    const float* Bfon  = (const float*)d_in[1];
    const int*   seg   = (const int*)d_in[2];
    const int*   src   = (const int*)d_in[3];
    const int*   dst   = (const int*)d_in[4];
    const float* convw = (const float*)d_in[5];
    const float* convb = (const float*)d_in[6];
    const float* W1    = (const float*)d_in[7];
    const float* b1    = (const float*)d_in[8];
    const float* W2    = (const float*)d_in[9];
    const float* b2    = (const float*)d_in[10];
    const float* fcw   = (const float*)d_in[11];
    const float* fcb   = (const float*)d_in[12];

    float* part = (float*)d_ws;                  // 100352 floats
    float* G    = part + BB * BPI * NN * 4;      // 4096 floats
    float* dump = G + BB * COUT;                 // 6272 floats (warm-keep)
    float* out  = (float*)d_out;

    k_conv_seg<<<NB1, 256, 0, stream>>>(Bfor, seg, convw, Bfon, part, dump);
    k_graph<<<BB, 256, 0, stream>>>(part, src, dst, convb,
                                    W1, b1, W2, b2, fcw, fcb, G);
    k_scale<<<NB1, 256, 0, stream>>>(Bfon, G, out);
}

// Round 6
// 51.398 us; speedup vs baseline: 1.1087x; 1.1087x over previous
//
#include <hip/hip_runtime.h>

#define NN 16
constexpr int BB = 32, CIN = 64, HH = 112, WW = 112;
constexpr int HWC = HH * WW;          // 12544
constexpr int COUT = 128, HW2 = 56 * 56;
constexpr int NE = 64;
constexpr int NQ = HWC / 4;           // 3136 float4 pixels per image
constexpr int BPI = 13;               // conv blocks per image (13*256 >= 3136)
constexpr int PF4 = COUT * HW2 / 4;   // 100352 float4 per batch
constexpr int SBPB = 25;              // scale blocks per batch

// ---------------- Kernel 1: fat-block 1x1 conv + direct segment scatter ----
// 256 threads/block, thread owns one pixel-quad across ALL 64 channels:
// 4 batches x 16 independent loads (16-deep MLP), no LDS combine, 1 barrier.
__global__ __launch_bounds__(256) void k_conv_seg(
    const float* __restrict__ Bfor, const int* __restrict__ seg,
    const float* __restrict__ convw, float* __restrict__ part)
{
    __shared__ float w[CIN];
    __shared__ float acc[8 * 80];       // [replica][node*5+st], bank-skewed
    const int tid = threadIdx.x;
    const int b   = blockIdx.x / BPI;
    const int blk = blockIdx.x % BPI;

    if (tid < CIN) w[tid] = convw[tid];
    for (int i = tid; i < 8 * 80; i += 256) acc[i] = 0.f;
    __syncthreads();

    const int q = blk * 256 + tid;      // quad id in image
    if (q < NQ) {
        const int p = q * 4;
        const float* base = Bfor + (size_t)b * CIN * HWC + p;

        float4 s = make_float4(0.f, 0.f, 0.f, 0.f);
        #pragma unroll
        for (int cb = 0; cb < 4; ++cb) {
            float4 v[16];
            #pragma unroll
            for (int j = 0; j < 16; ++j)
                v[j] = *reinterpret_cast<const float4*>(base + (size_t)(cb * 16 + j) * HWC);
            #pragma unroll
            for (int j = 0; j < 16; ++j) {
                const float wc = w[cb * 16 + j];
                s.x = fmaf(v[j].x, wc, s.x);
                s.y = fmaf(v[j].y, wc, s.y);
                s.z = fmaf(v[j].z, wc, s.z);
                s.w = fmaf(v[j].w, wc, s.w);
            }
        }

        const int4 sg = *reinterpret_cast<const int4*>(seg + (size_t)b * HWC + p);
        const float row  = (float)(p / WW);   // WW%4==0 -> all 4 px same row
        const float col0 = (float)(p % WW);
        const int k = tid & 7;                // replica
        float* a0 = &acc[k * 80];
        atomicAdd(a0 + sg.x * 5 + 0, row);
        atomicAdd(a0 + sg.x * 5 + 1, col0);
        atomicAdd(a0 + sg.x * 5 + 2, s.x);
        atomicAdd(a0 + sg.x * 5 + 3, 1.f);
        atomicAdd(a0 + sg.y * 5 + 0, row);
        atomicAdd(a0 + sg.y * 5 + 1, col0 + 1.f);
        atomicAdd(a0 + sg.y * 5 + 2, s.y);
        atomicAdd(a0 + sg.y * 5 + 3, 1.f);
        atomicAdd(a0 + sg.z * 5 + 0, row);
        atomicAdd(a0 + sg.z * 5 + 1, col0 + 2.f);
        atomicAdd(a0 + sg.z * 5 + 2, s.z);
        atomicAdd(a0 + sg.z * 5 + 3, 1.f);
        atomicAdd(a0 + sg.w * 5 + 0, row);
        atomicAdd(a0 + sg.w * 5 + 1, col0 + 3.f);
        atomicAdd(a0 + sg.w * 5 + 2, s.w);
        atomicAdd(a0 + sg.w * 5 + 3, 1.f);
    }
    __syncthreads();

    if (tid < NN * 4) {
        const int node = tid >> 2, st = tid & 3;
        float v = 0.f;
        #pragma unroll
        for (int k = 0; k < 8; ++k) v += acc[k * 80 + node * 5 + st];
        part[((b * BPI + blk) * NN + node) * 4 + st] = v;
    }
}

// ------- Kernel 2: fused graph stage (redundant per block) + broadcast scale
__global__ __launch_bounds__(256) void k_graph_scale(
    const float* __restrict__ part, const int* __restrict__ src,
    const int* __restrict__ dst,  const float* __restrict__ convb,
    const float* __restrict__ W1, const float* __restrict__ b1,
    const float* __restrict__ W2, const float* __restrict__ b2,
    const float* __restrict__ fcw, const float* __restrict__ fcb,
    const float* __restrict__ Bfon, float* __restrict__ out)
{
    const int b    = blockIdx.x / SBPB;
    const int blkb = blockIdx.x % SBPB;
    const int tid  = threadIdx.x;

    __shared__ float X[NN][4];
    __shared__ float A[NN][NN];
    __shared__ float nrm[NN];
    __shared__ float h1s[NN][32];
    __shared__ float agg[NN][32];
    __shared__ float gpart[2][COUT];
    __shared__ float Gs[COUT];

    // ---- Phase A: tiny graph network (redundant across SBPB blocks) ----
    if (tid < 64) {        // reduce 13 conv-block partials, coalesced per iter
        const int node = tid >> 2, st = tid & 3;
        float v = 0.f;
        #pragma unroll
        for (int k = 0; k < BPI; ++k) v += part[((b * BPI + k) * NN + node) * 4 + st];
        X[node][st] = v;
    }
    for (int i = tid; i < NN * NN; i += 256) ((float*)A)[i] = 0.f;
    __syncthreads();

    if (tid < NN) {        // raw sums -> features (conv bias folded in)
        const float cnt = X[tid][3];
        const float cs  = fmaxf(cnt, 1.f);
        X[tid][0] = X[tid][0] / cs;
        X[tid][1] = X[tid][1] / cs;
        X[tid][2] = (X[tid][2] + cnt * convb[0]) / cs;
    }
    __syncthreads();

    // normalize feature cols 2,3 across nodes (mean, std ddof=1)
    if (tid < 2) {
        const int c = 2 + tid;
        float mu = 0.f;
        for (int i = 0; i < NN; ++i) mu += X[i][c];
        mu *= (1.f / NN);
        float var = 0.f;
        for (int i = 0; i < NN; ++i) { const float d = X[i][c] - mu; var = fmaf(d, d, var); }
        var *= (1.f / (NN - 1));
        const float inv = 1.f / (sqrtf(var) + 1.f);
        for (int i = 0; i < NN; ++i) X[i][c] = (X[i][c] - mu) * inv;
    }
    // build adjacency (idempotent set-to-1)
    if (tid >= 64 && tid < 64 + NE) {
        const int e = tid - 64;
        const int s = src[b * NE + e], d = dst[b * NE + e];
        A[s][d] = 1.f;
        A[d][s] = 1.f;
    }
    __syncthreads();

    if (tid < NN) {
        float rs = 0.f;
        for (int j = 0; j < NN; ++j) rs += A[tid][j];
        nrm[tid] = 1.f / sqrtf(fmaxf(rs, 1.f));
    }
    __syncthreads();

    if (tid < NN * 4) {    // agg1 (16x4)
        const int i = tid >> 2, k = tid & 3;
        float s = 0.f;
        for (int j = 0; j < NN; ++j) s = fmaf(A[i][j] * nrm[j], X[j][k], s);
        agg[i][k] = s;
    }
    __syncthreads();

    for (int t = tid; t < NN * 32; t += 256) {   // h1 (16x32)
        const int i = t >> 5, f = t & 31;
        float s = 0.f;
        #pragma unroll
        for (int k = 0; k < 4; ++k) s = fmaf(agg[i][k], W1[k * 32 + f], s);
        h1s[i][f] = fmaxf(fmaf(nrm[i], s, b1[f]), 0.f);
    }
    __syncthreads();

    for (int t = tid; t < NN * 32; t += 256) {   // agg2 (16x32)
        const int i = t >> 5, k = t & 31;
        float s = 0.f;
        for (int j = 0; j < NN; ++j) s = fmaf(A[i][j] * nrm[j], h1s[j][k], s);
        agg[i][k] = s;
    }
    __syncthreads();

    {   // h2 + FC, i-range split across 2 half-blocks
        const int f = tid & 127, half = tid >> 7;
        float g = 0.f;
        const float bf = b2[f];
        for (int i = half * 8; i < half * 8 + 8; ++i) {
            float s = 0.f;
            #pragma unroll
            for (int k = 0; k < 32; ++k) s = fmaf(agg[i][k], W2[k * COUT + f], s);
            g = fmaf(fcw[i], fmaxf(fmaf(nrm[i], s, bf), 0.f), g);
        }
        gpart[half][f] = g;
    }
    __syncthreads();
    if (tid < COUT) Gs[tid] = gpart[0][tid] + gpart[1][tid] + fcb[0];
    __syncthreads();

    // ---- Phase B: out[b,c,:,:] = Gs[c] * B_fon[b,c,:,:] (this block's slice)
    const float4* bf4 = reinterpret_cast<const float4*>(Bfon) + (size_t)b * PF4;
    float4*       ob4 = reinterpret_cast<float4*>(out)        + (size_t)b * PF4;
    for (int t = blkb * 256 + tid; t < PF4; t += SBPB * 256) {
        const float4 v = bf4[t];
        const float  g = Gs[t / (HW2 / 4)];   // 784 float4 per (b,c) plane
        ob4[t] = make_float4(v.x * g, v.y * g, v.z * g, v.w * g);
    }
}

extern "C" void kernel_launch(void* const* d_in, const int* in_sizes, int n_in,
                              void* d_out, int out_size, void* d_ws, size_t ws_size,
                              hipStream_t stream)
{
    const float* Bfor  = (const float*)d_in[0];
    const float* Bfon  = (const float*)d_in[1];
    const int*   seg   = (const int*)d_in[2];
    const int*   src   = (const int*)d_in[3];
    const int*   dst   = (const int*)d_in[4];
    const float* convw = (const float*)d_in[5];
    const float* convb = (const float*)d_in[6];
    const float* W1    = (const float*)d_in[7];
    const float* b1    = (const float*)d_in[8];
    const float* W2    = (const float*)d_in[9];
    const float* b2    = (const float*)d_in[10];
    const float* fcw   = (const float*)d_in[11];
    const float* fcb   = (const float*)d_in[12];

    float* part = (float*)d_ws;           // BB*BPI*NN*4 = 26624 floats
    float* out  = (float*)d_out;

    k_conv_seg<<<BB * BPI, 256, 0, stream>>>(Bfor, seg, convw, part);
    k_graph_scale<<<BB * SBPB, 256, 0, stream>>>(part, src, dst, convb,
                                                 W1, b1, W2, b2, fcw, fcb,
                                                 Bfon, out);
}